// Round 5
// baseline (602.798 us; speedup 1.0000x reference)
//
#include <hip/hip_runtime.h>

// ---- problem constants ----
constexpr int B_  = 128;
constexpr int T_  = 24;
constexpr int E_  = 512;
constexpr int H_  = 512;
constexpr int V_  = 10000;
constexpr int G4  = 2048;   // 4*H
constexpr int TP1 = 25;     // T+1

typedef __attribute__((ext_vector_type(8))) short bf16x8;   // 8 bf16 = 4 VGPR
typedef __attribute__((ext_vector_type(4))) short short4v;  // 4 bf16 = 8 B
typedef __attribute__((ext_vector_type(4))) float f32x4;

#define MFMA_16x16x32_BF16(a, b, c) __builtin_amdgcn_mfma_f32_16x16x32_bf16((a), (b), (c), 0, 0, 0)

// fp32 -> bf16 round-to-nearest-even (bit-level, no header ABI dependence)
__device__ inline unsigned short f2bf(float f) {
    unsigned int u = __float_as_uint(f);
    unsigned int r = (u + 0x7FFFu + ((u >> 16) & 1u)) >> 16;
    return (unsigned short)r;
}

// ---------------------------------------------------------------------------
// Bulk fp32 -> bf16 convert (float4 in, short4 out). n4 = elem_count/4.
// ---------------------------------------------------------------------------
__global__ __launch_bounds__(256) void k_cvt(const float* __restrict__ src,
                                             unsigned short* __restrict__ dst, int n4) {
    int i = blockIdx.x * 256 + threadIdx.x;
    if (i >= n4) return;
    float4 v = ((const float4*)src)[i];
    short4v o;
    o[0] = (short)f2bf(v.x); o[1] = (short)f2bf(v.y);
    o[2] = (short)f2bf(v.z); o[3] = (short)f2bf(v.w);
    ((short4v*)dst)[i] = o;
}

// ---------------------------------------------------------------------------
// Embedding gather -> bf16, padding_idx(0) -> zeros.
// Xemb[m][k], m = t*128 + b, 3072 rows x 512.
// ---------------------------------------------------------------------------
__global__ __launch_bounds__(256) void k_embed(const float* __restrict__ Wemb,
                                               const int* __restrict__ captions,
                                               unsigned short* __restrict__ Xemb) {
    int i = blockIdx.x * 256 + threadIdx.x;     // one thread per 4 elems
    if (i >= 3072 * 128) return;
    int row = i >> 7;                           // m = t*128 + b
    int k4  = i & 127;
    int b = row & 127, t = row >> 7;
    int tok = captions[b * T_ + t];
    short4v o = {0, 0, 0, 0};
    if (tok > 0 && tok < V_) {                  // tok==0 is padding -> zeros
        float4 v = ((const float4*)(Wemb + (long)tok * E_))[k4];
        o[0] = (short)f2bf(v.x); o[1] = (short)f2bf(v.y);
        o[2] = (short)f2bf(v.z); o[3] = (short)f2bf(v.w);
    }
    ((short4v*)Xemb)[(long)row * 128 + k4] = o;
}

// ---------------------------------------------------------------------------
// t=0 one-hot rows (fp32) + (captions_length - 1) tail
// ---------------------------------------------------------------------------
__global__ __launch_bounds__(256) void k_start(float* __restrict__ out,
                                               const int* __restrict__ cap_len) {
    int idx = blockIdx.x * 256 + threadIdx.x;
    constexpr int Q  = V_ / 4;                  // 2500 float4 per row
    constexpr int NQ = B_ * Q;                  // 320000
    float4 zero = {0.f, 0.f, 0.f, 0.f};
    float4 one1 = {0.f, 1.f, 0.f, 0.f};         // one-hot at v=1
    for (int i = idx; i < NQ; i += gridDim.x * 256) {
        int b = i / Q;
        int q = i - b * Q;
        ((float4*)out)[(long)b * (TP1 * V_ / 4) + q] = (q == 0) ? one1 : zero;
    }
    if (idx < B_) {
        out[(size_t)B_ * TP1 * V_ + idx] = (float)(cap_len[idx] - 1);
    }
}

// ---------------------------------------------------------------------------
// Step GEMM: gates[b][n] = Xemb_t[b].Wih[n] + h[b].Whh[n] + bih[n] + bhh[n]
// M=128 (8 MI), N=2048 (128 NI). One 16x16x32 MFMA tile/wave, K=1024 total.
// ---------------------------------------------------------------------------
__global__ __launch_bounds__(256) void k_stepgemm(const unsigned short* __restrict__ Xt,
                                                  const unsigned short* __restrict__ hbf,
                                                  const unsigned short* __restrict__ Wih,
                                                  const unsigned short* __restrict__ Whh,
                                                  const float* __restrict__ bih,
                                                  const float* __restrict__ bhh,
                                                  float* __restrict__ gates) {
    int wid  = blockIdx.x * 4 + (threadIdx.x >> 6);  // 0..1023
    int lane = threadIdx.x & 63;
    int MI = wid >> 7;        // 0..7
    int NI = wid & 127;       // 0..127
    int lm = lane & 15, lq = lane >> 4;

    int m = MI * 16 + lm;
    const short* Ax = (const short*)Xt  + (long)m * E_;
    const short* Ah = (const short*)hbf + (long)m * H_;
    const short* Bi = (const short*)Wih + (long)(NI * 16 + lm) * E_;
    const short* Bh = (const short*)Whh + (long)(NI * 16 + lm) * H_;

    f32x4 acc = {};
    #pragma unroll
    for (int k0 = 0; k0 < E_; k0 += 32) {
        int ko = k0 + lq * 8;
        acc = MFMA_16x16x32_BF16(*(const bf16x8*)(Ax + ko), *(const bf16x8*)(Bi + ko), acc);
    }
    #pragma unroll
    for (int k0 = 0; k0 < H_; k0 += 32) {
        int ko = k0 + lq * 8;
        acc = MFMA_16x16x32_BF16(*(const bf16x8*)(Ah + ko), *(const bf16x8*)(Bh + ko), acc);
    }

    int n = NI * 16 + lm;
    float bias = bih[n] + bhh[n];
    #pragma unroll
    for (int r = 0; r < 4; r++) {
        int mm = MI * 16 + lq * 4 + r;               // C/D layout: row = lq*4+r
        gates[(long)mm * G4 + n] = acc[r] + bias;
    }
}

// ---------------------------------------------------------------------------
// LSTM cell elementwise. 128*512 = 65536 threads. c fp32; h -> bf16.
// ---------------------------------------------------------------------------
__global__ __launch_bounds__(256) void k_cell(const float* __restrict__ gates,
                                              float* __restrict__ c,
                                              unsigned short* __restrict__ hbf,
                                              unsigned short* __restrict__ Hall_t,
                                              int t) {
    int idx = blockIdx.x * 256 + threadIdx.x;   // 0..65535
    int b = idx >> 9, hh = idx & 511;
    const float* g = gates + (long)b * G4;
    float gi = g[hh];
    float gf = g[hh + 512];
    float gg = g[hh + 1024];
    float go = g[hh + 1536];
    float cprev = (t == 0) ? 0.f : c[idx];
    float si = 1.f / (1.f + expf(-gi));
    float sf = 1.f / (1.f + expf(-gf));
    float so = 1.f / (1.f + expf(-go));
    float cn = sf * cprev + si * tanhf(gg);
    float hn = so * tanhf(cn);
    c[idx] = cn;
    unsigned short hb = f2bf(hn);
    hbf[idx] = hb;
    Hall_t[idx] = hb;
}

// ---------------------------------------------------------------------------
// Logits: Hall[3072,512](bf16) @ Wout_bf^T + b_out(f32) -> fp32 out[b][t+1][v]
// 64x64 tile per wave; m = t*128 + b.
// ---------------------------------------------------------------------------
__global__ __launch_bounds__(256) void k_logits(const unsigned short* __restrict__ Hall,
                                                const unsigned short* __restrict__ Wout,
                                                const float* __restrict__ bout,
                                                float* __restrict__ out) {
    constexpr int NTILES = 157;                  // ceil(10000/64)
    int wid = blockIdx.x * 4 + (threadIdx.x >> 6);
    if (wid >= 48 * NTILES) return;
    int MI = wid / NTILES;
    int NI = wid - MI * NTILES;
    int lane = threadIdx.x & 63;
    int lm = lane & 15, lq = lane >> 4;

    const short* As = (const short*)Hall;
    const short* Bs = (const short*)Wout;

    f32x4 acc[4][4] = {};
    for (int k0 = 0; k0 < 512; k0 += 32) {
        int ko = k0 + lq * 8;
        bf16x8 af[4], bfr[4];
        #pragma unroll
        for (int mi = 0; mi < 4; mi++)
            af[mi] = *(const bf16x8*)(As + (long)(MI * 64 + mi * 16 + lm) * 512 + ko);
        #pragma unroll
        for (int ni = 0; ni < 4; ni++) {
            int n = NI * 64 + ni * 16 + lm;
            if (n >= V_) n = V_ - 1;             // clamp: garbage cols never stored
            bfr[ni] = *(const bf16x8*)(Bs + (long)n * 512 + ko);
        }
        #pragma unroll
        for (int mi = 0; mi < 4; mi++)
            #pragma unroll
            for (int ni = 0; ni < 4; ni++)
                acc[mi][ni] = MFMA_16x16x32_BF16(af[mi], bfr[ni], acc[mi][ni]);
    }

    #pragma unroll
    for (int mi = 0; mi < 4; mi++) {
        #pragma unroll
        for (int r = 0; r < 4; r++) {
            int m = MI * 64 + mi * 16 + lq * 4 + r;  // m = t*128 + b
            int b = m & 127, t = m >> 7;
            float* orow = out + ((size_t)b * TP1 + t + 1) * V_;
            #pragma unroll
            for (int ni = 0; ni < 4; ni++) {
                int n = NI * 64 + ni * 16 + lm;
                if (n < V_) orow[n] = acc[mi][ni][r] + bout[n];
            }
        }
    }
}

// ---------------------------------------------------------------------------
extern "C" void kernel_launch(void* const* d_in, const int* in_sizes, int n_in,
                              void* d_out, int out_size, void* d_ws, size_t ws_size,
                              hipStream_t stream) {
    const float* images   = (const float*)d_in[0];
    const int*   captions = (const int*)d_in[1];
    const int*   cap_len  = (const int*)d_in[2];
    const float* Wemb     = (const float*)d_in[3];
    const float* Wih      = (const float*)d_in[4];
    const float* Whh      = (const float*)d_in[5];
    const float* bih      = (const float*)d_in[6];
    const float* bhh      = (const float*)d_in[7];
    const float* Wout     = (const float*)d_in[8];
    const float* bout     = (const float*)d_in[9];
    float* out = (float*)d_out;
    (void)ws_size;

    // workspace layout (total ~22.2 MB, all offsets 256B-aligned)
    char* ws = (char*)d_ws;
    unsigned short* Wih_bf  = (unsigned short*)(ws);              //  2,097,152 B
    unsigned short* Whh_bf  = (unsigned short*)(ws + 2097152);    //  2,097,152 B
    unsigned short* Wout_bf = (unsigned short*)(ws + 4194304);    // 10,240,000 B
    unsigned short* Xemb    = (unsigned short*)(ws + 14434304);   //  3,145,728 B
    unsigned short* Hall    = (unsigned short*)(ws + 17580032);   //  3,145,728 B
    unsigned short* hbf     = (unsigned short*)(ws + 20725760);   //    131,072 B
    float*          cbuf    = (float*)(ws + 20856832);            //    262,144 B
    float*          gates   = (float*)(ws + 21118976);            //  1,048,576 B

    // fp32 -> bf16 weight staging
    k_cvt<<<1024, 256, 0, stream>>>(Wih,    Wih_bf,  G4 * E_ / 4);       // 262144
    k_cvt<<<1024, 256, 0, stream>>>(Whh,    Whh_bf,  G4 * H_ / 4);       // 262144
    k_cvt<<<5000, 256, 0, stream>>>(Wout,   Wout_bf, V_ * H_ / 4);       // 1280000
    k_cvt<<<  64, 256, 0, stream>>>(images, hbf,     B_ * H_ / 4);       // 16384
    k_embed<<<1536, 256, 0, stream>>>(Wemb, captions, Xemb);

    // t=0 one-hot rows + length tail
    k_start<<<1250, 256, 0, stream>>>(out, cap_len);

    // serial recurrence
    for (int t = 0; t < T_; t++) {
        k_stepgemm<<<256, 256, 0, stream>>>(Xemb + (long)t * B_ * E_, hbf,
                                            Wih_bf, Whh_bf, bih, bhh, gates);
        k_cell<<<256, 256, 0, stream>>>(gates, cbuf, hbf, Hall + (long)t * B_ * H_, t);
    }

    // all logits in one shot (48*157 = 7536 wave-tiles / 4 = 1884 blocks)
    k_logits<<<1884, 256, 0, stream>>>(Hall, Wout_bf, bout, out);
}